// Round 2
// baseline (244.112 us; speedup 1.0000x reference)
//
#include <hip/hip_runtime.h>
#include <hip/hip_bf16.h>
#include <cstdint>

typedef __attribute__((ext_vector_type(8))) short bf16x8;
typedef __attribute__((ext_vector_type(4))) short bf16x4;
typedef __attribute__((ext_vector_type(4))) float f32x4;

__device__ __forceinline__ short cvt_bf16(float f) {
  union { float f; uint32_t u; } x; x.f = f;
  uint32_t r = x.u + 0x7FFFu + ((x.u >> 16) & 1u);  // RNE
  return (short)(r >> 16);
}
__device__ __forceinline__ float bf16_to_f(short s) {
  union { uint32_t u; float f; } x; x.u = ((uint32_t)(uint16_t)s) << 16;
  return x.f;
}

// tanh(x) = 1 - 2/(e^{2x}+1); exp2 form never overflows the denominator.
__device__ __forceinline__ float tanh_fast(float x) {
  float e = __builtin_amdgcn_exp2f(x * 2.8853900817779268f);  // 2*log2(e)
  return 1.0f - 2.0f * __builtin_amdgcn_rcpf(e + 1.0f);
}

// ---------- f32 -> (hi,lo) bf16 split convert ----------
__global__ __launch_bounds__(256) void k_convert_split(const float* __restrict__ in,
                                                       short* __restrict__ hi,
                                                       short* __restrict__ lo, int n4) {
  int i = blockIdx.x * 256 + threadIdx.x;
  int stride = gridDim.x * 256;
  for (; i < n4; i += stride) {
    float4 v = ((const float4*)in)[i];
    bf16x4 h, l;
    h.x = cvt_bf16(v.x); h.y = cvt_bf16(v.y); h.z = cvt_bf16(v.z); h.w = cvt_bf16(v.w);
    l.x = cvt_bf16(v.x - bf16_to_f(h.x));
    l.y = cvt_bf16(v.y - bf16_to_f(h.y));
    l.z = cvt_bf16(v.z - bf16_to_f(h.z));
    l.w = cvt_bf16(v.w - bf16_to_f(h.w));
    ((bf16x4*)hi)[i] = h;
    ((bf16x4*)lo)[i] = l;
  }
}

// ---------- LDS-tiled transpose + f32->bf16 split: out[c*R+r] = in[r*C+c] ----------
__global__ __launch_bounds__(256) void k_transpose_split(const float* __restrict__ in,
                                                         short* __restrict__ hi,
                                                         short* __restrict__ lo,
                                                         int R, int C) {
  __shared__ float tile[32][33];
  int r0 = blockIdx.x * 32, c0 = blockIdx.y * 32;
  int j = threadIdx.x & 31, i0 = threadIdx.x >> 5;
  #pragma unroll
  for (int i = i0; i < 32; i += 8) {
    int c = c0 + j;
    tile[i][j] = (c < C) ? in[(size_t)(r0 + i) * C + c] : 0.f;
  }
  __syncthreads();
  #pragma unroll
  for (int i = i0; i < 32; i += 8) {
    float v = tile[j][i];
    short h = cvt_bf16(v);
    hi[(size_t)(c0 + i) * R + r0 + j] = h;
    lo[(size_t)(c0 + i) * R + r0 + j] = cvt_bf16(v - bf16_to_f(h));
  }
}

// ---------- plain transpose + cvt (for w4, zero-pad cols >= C) ----------
__global__ __launch_bounds__(256) void k_transpose_cvt(const float* __restrict__ in,
                                                       short* __restrict__ out,
                                                       int R, int C) {
  __shared__ float tile[32][33];
  int r0 = blockIdx.x * 32, c0 = blockIdx.y * 32;
  int j = threadIdx.x & 31, i0 = threadIdx.x >> 5;
  #pragma unroll
  for (int i = i0; i < 32; i += 8) {
    int c = c0 + j;
    tile[i][j] = (c < C) ? in[(size_t)(r0 + i) * C + c] : 0.f;
  }
  __syncthreads();
  #pragma unroll
  for (int i = i0; i < 32; i += 8)
    out[(size_t)(c0 + i) * R + r0 + j] = cvt_bf16(tile[j][i]);
}

// ---------- fb[b][t][a] = text[b,t,:] . w2[:,a] + bias[a]  (K=300, exact f32) ----------
__global__ __launch_bounds__(256) void k_fb(const float* __restrict__ text,
                                            const float* __restrict__ w2,
                                            const float* __restrict__ bias,
                                            float* __restrict__ fb) {
  int b = blockIdx.x, t0 = blockIdx.y * 8, a = threadIdx.x;
  float acc[8] = {0.f,0.f,0.f,0.f,0.f,0.f,0.f,0.f};
  const float* tp = text + ((size_t)b * 40 + t0) * 300;
  for (int k = 0; k < 300; k++) {
    float wv = w2[k * 256 + a];
    #pragma unroll
    for (int j = 0; j < 8; j++) acc[j] += tp[j * 300 + k] * wv;
  }
  float bv = bias[a];
  #pragma unroll
  for (int j = 0; j < 8; j++)
    fb[((size_t)b * 40 + t0 + j) * 256 + a] = acc[j] + bv;
}

// ---------- bf16 MFMA GEMM: C[MxN(ldc)] = A[MxK] * BT[NxK]^T (+bias) ----------
__global__ __launch_bounds__(256) void k_gemm(const short* __restrict__ A,
                                              const short* __restrict__ BT,
                                              const float* __restrict__ bias,
                                              float* __restrict__ C,
                                              int K, int ldc, int nstore) {
  __shared__ __align__(16) short As[64][72];
  __shared__ __align__(16) short Bs[64][72];
  int m0 = blockIdx.x * 64, n0 = blockIdx.y * 64;
  int tid = threadIdx.x, lane = tid & 63, wave = tid >> 6;
  int wm = (wave & 1) * 32, wn = (wave >> 1) * 32;
  int srow = tid >> 3, sseg = (tid & 7) * 8;
  f32x4 acc[2][2];
  #pragma unroll
  for (int i = 0; i < 2; i++)
    #pragma unroll
    for (int j = 0; j < 2; j++) acc[i][j] = (f32x4){0.f, 0.f, 0.f, 0.f};
  int mrow = lane & 15, quad = lane >> 4;

  for (int k0 = 0; k0 < K; k0 += 64) {
    bf16x8 a0 = *(const bf16x8*)(A + (size_t)(m0 + srow) * K + k0 + sseg);
    bf16x8 a1 = *(const bf16x8*)(A + (size_t)(m0 + srow + 32) * K + k0 + sseg);
    bf16x8 b0 = *(const bf16x8*)(BT + (size_t)(n0 + srow) * K + k0 + sseg);
    bf16x8 b1 = *(const bf16x8*)(BT + (size_t)(n0 + srow + 32) * K + k0 + sseg);
    __syncthreads();
    *(bf16x8*)&As[srow][sseg] = a0;
    *(bf16x8*)&As[srow + 32][sseg] = a1;
    *(bf16x8*)&Bs[srow][sseg] = b0;
    *(bf16x8*)&Bs[srow + 32][sseg] = b1;
    __syncthreads();
    #pragma unroll
    for (int ks = 0; ks < 2; ks++) {
      int kk = ks * 32 + quad * 8;
      bf16x8 af0 = *(const bf16x8*)&As[wm + mrow][kk];
      bf16x8 af1 = *(const bf16x8*)&As[wm + 16 + mrow][kk];
      bf16x8 bf0 = *(const bf16x8*)&Bs[wn + mrow][kk];
      bf16x8 bf1 = *(const bf16x8*)&Bs[wn + 16 + mrow][kk];
      acc[0][0] = __builtin_amdgcn_mfma_f32_16x16x32_bf16(af0, bf0, acc[0][0], 0, 0, 0);
      acc[0][1] = __builtin_amdgcn_mfma_f32_16x16x32_bf16(af0, bf1, acc[0][1], 0, 0, 0);
      acc[1][0] = __builtin_amdgcn_mfma_f32_16x16x32_bf16(af1, bf0, acc[1][0], 0, 0, 0);
      acc[1][1] = __builtin_amdgcn_mfma_f32_16x16x32_bf16(af1, bf1, acc[1][1], 0, 0, 0);
    }
  }
  int rbase = quad * 4;
  #pragma unroll
  for (int i = 0; i < 2; i++)
    #pragma unroll
    for (int j = 0; j < 2; j++) {
      int col = n0 + wn + j * 16 + mrow;
      if (col < nstore) {
        float bv = bias ? bias[col] : 0.f;
        #pragma unroll
        for (int r = 0; r < 4; r++) {
          int row = m0 + wm + i * 16 + rbase + r;
          C[(size_t)row * ldc + col] = acc[i][j][r] + bv;
        }
      }
    }
}

// ---------- split-bf16 MFMA GEMM (~f32 precision): C = (Ah+Al) * (Bh+Bl)^T ----------
// accumulates AhBh + AhBl + AlBh; rel err ~2^-17.
__global__ __launch_bounds__(256) void k_gemm_split(const short* __restrict__ Ah,
                                                    const short* __restrict__ Al,
                                                    const short* __restrict__ BTh,
                                                    const short* __restrict__ BTl,
                                                    float* __restrict__ C,
                                                    int K, int ldc) {
  __shared__ __align__(16) short Ash[64][72];
  __shared__ __align__(16) short Asl[64][72];
  __shared__ __align__(16) short Bsh[64][72];
  __shared__ __align__(16) short Bsl[64][72];
  int m0 = blockIdx.x * 64, n0 = blockIdx.y * 64;
  int tid = threadIdx.x, lane = tid & 63, wave = tid >> 6;
  int wm = (wave & 1) * 32, wn = (wave >> 1) * 32;
  int srow = tid >> 3, sseg = (tid & 7) * 8;
  f32x4 acc[2][2];
  #pragma unroll
  for (int i = 0; i < 2; i++)
    #pragma unroll
    for (int j = 0; j < 2; j++) acc[i][j] = (f32x4){0.f, 0.f, 0.f, 0.f};
  int mrow = lane & 15, quad = lane >> 4;

  for (int k0 = 0; k0 < K; k0 += 64) {
    size_t aoff0 = (size_t)(m0 + srow) * K + k0 + sseg;
    size_t aoff1 = aoff0 + (size_t)32 * K;
    size_t boff0 = (size_t)(n0 + srow) * K + k0 + sseg;
    size_t boff1 = boff0 + (size_t)32 * K;
    bf16x8 a0h = *(const bf16x8*)(Ah + aoff0);
    bf16x8 a1h = *(const bf16x8*)(Ah + aoff1);
    bf16x8 a0l = *(const bf16x8*)(Al + aoff0);
    bf16x8 a1l = *(const bf16x8*)(Al + aoff1);
    bf16x8 b0h = *(const bf16x8*)(BTh + boff0);
    bf16x8 b1h = *(const bf16x8*)(BTh + boff1);
    bf16x8 b0l = *(const bf16x8*)(BTl + boff0);
    bf16x8 b1l = *(const bf16x8*)(BTl + boff1);
    __syncthreads();
    *(bf16x8*)&Ash[srow][sseg] = a0h;  *(bf16x8*)&Ash[srow + 32][sseg] = a1h;
    *(bf16x8*)&Asl[srow][sseg] = a0l;  *(bf16x8*)&Asl[srow + 32][sseg] = a1l;
    *(bf16x8*)&Bsh[srow][sseg] = b0h;  *(bf16x8*)&Bsh[srow + 32][sseg] = b1h;
    *(bf16x8*)&Bsl[srow][sseg] = b0l;  *(bf16x8*)&Bsl[srow + 32][sseg] = b1l;
    __syncthreads();
    #pragma unroll
    for (int ks = 0; ks < 2; ks++) {
      int kk = ks * 32 + quad * 8;
      bf16x8 ah[2], al[2], bh[2], bl[2];
      ah[0] = *(const bf16x8*)&Ash[wm + mrow][kk];
      ah[1] = *(const bf16x8*)&Ash[wm + 16 + mrow][kk];
      al[0] = *(const bf16x8*)&Asl[wm + mrow][kk];
      al[1] = *(const bf16x8*)&Asl[wm + 16 + mrow][kk];
      bh[0] = *(const bf16x8*)&Bsh[wn + mrow][kk];
      bh[1] = *(const bf16x8*)&Bsh[wn + 16 + mrow][kk];
      bl[0] = *(const bf16x8*)&Bsl[wn + mrow][kk];
      bl[1] = *(const bf16x8*)&Bsl[wn + 16 + mrow][kk];
      #pragma unroll
      for (int i = 0; i < 2; i++)
        #pragma unroll
        for (int j = 0; j < 2; j++) {
          acc[i][j] = __builtin_amdgcn_mfma_f32_16x16x32_bf16(ah[i], bh[j], acc[i][j], 0, 0, 0);
          acc[i][j] = __builtin_amdgcn_mfma_f32_16x16x32_bf16(ah[i], bl[j], acc[i][j], 0, 0, 0);
          acc[i][j] = __builtin_amdgcn_mfma_f32_16x16x32_bf16(al[i], bh[j], acc[i][j], 0, 0, 0);
        }
    }
  }
  int rbase = quad * 4;
  #pragma unroll
  for (int i = 0; i < 2; i++)
    #pragma unroll
    for (int j = 0; j < 2; j++) {
      int col = n0 + wn + j * 16 + mrow;
      #pragma unroll
      for (int r = 0; r < 4; r++) {
        int row = m0 + wm + i * 16 + rbase + r;
        C[(size_t)row * ldc + col] = acc[i][j][r];
      }
    }
}

// ---------- fused middle: logits -> softmax -> text_attn -> tanh(cont) as bf16 ----------
#define FBS 258
__global__ __launch_bounds__(320) void k_middle(const float* __restrict__ e,
                                                const float* __restrict__ fb,
                                                const float* __restrict__ w3,
                                                const float* __restrict__ bias,
                                                short* __restrict__ cont) {
  __shared__ __align__(16) float fbs[40 * FBS];
  __shared__ __align__(16) float es[8 * FBS];
  __shared__ float lg[8][40];
  __shared__ float attn[8][44];
  int row0 = blockIdx.x * 8;
  int b = row0 >> 9;
  int tid = threadIdx.x;

  const float2* fsrc = (const float2*)(fb + (size_t)b * 40 * 256);
  for (int i = tid; i < 40 * 128; i += 320) {
    int t = i >> 7, c = i & 127;
    *(float2*)&fbs[t * FBS + 2 * c] = fsrc[i];
  }
  const float2* esrc = (const float2*)(e + (size_t)row0 * 256);
  for (int i = tid; i < 8 * 128; i += 320) {
    int r2 = i >> 7, c = i & 127;
    *(float2*)&es[r2 * FBS + 2 * c] = esrc[i];
  }
  __syncthreads();

  int r = tid / 40, t = tid - r * 40;
  {
    const float* er = es + r * FBS;
    const float* ft = fbs + t * FBS;
    float acc = 0.f;
    #pragma unroll 4
    for (int a = 0; a < 256; a += 2) {
      float2 ev = *(const float2*)(er + a);
      float2 fv = *(const float2*)(ft + a);
      float2 wv = *(const float2*)(w3 + a);
      acc += tanh_fast(ev.x + fv.x) * wv.x;
      acc += tanh_fast(ev.y + fv.y) * wv.y;
    }
    lg[r][t] = acc;
  }
  __syncthreads();

  {
    float mx = -1e30f;
    for (int j = 0; j < 40; j++) mx = fmaxf(mx, lg[r][j]);
    float s = 0.f;
    for (int j = 0; j < 40; j++)
      s += __builtin_amdgcn_exp2f((lg[r][j] - mx) * 1.4426950408889634f);
    attn[r][t] = __builtin_amdgcn_exp2f((lg[r][t] - mx) * 1.4426950408889634f)
               * __builtin_amdgcn_rcpf(s);
  }
  __syncthreads();

  if (tid < 128) {
    int a2 = tid * 2;
    float tax[8], tay[8];
    #pragma unroll
    for (int rr = 0; rr < 8; rr++) { tax[rr] = 0.f; tay[rr] = 0.f; }
    for (int j = 0; j < 40; j++) {
      float2 fv = *(const float2*)&fbs[j * FBS + a2];
      #pragma unroll
      for (int rr = 0; rr < 8; rr++) {
        float w = attn[rr][j];
        tax[rr] += w * fv.x; tay[rr] += w * fv.y;
      }
    }
    float2 bv = *(const float2*)(bias + a2);
    #pragma unroll
    for (int rr = 0; rr < 8; rr++) {
      float2 ev = *(const float2*)&es[rr * FBS + a2];
      float tx = tax[rr] - bv.x, ty = tay[rr] - bv.y;
      size_t orow = (size_t)(row0 + rr) * 1024;
      auto st = [&](int off, float x, float y) {
        uint32_t p = (uint32_t)(uint16_t)cvt_bf16(x) |
                     ((uint32_t)(uint16_t)cvt_bf16(y) << 16);
        *(uint32_t*)(cont + orow + off + a2) = p;
      };
      st(0,   tanh_fast(ev.x),        tanh_fast(ev.y));
      st(256, tanh_fast(tx),          tanh_fast(ty));
      st(512, tanh_fast(ev.x * tx),   tanh_fast(ev.y * ty));
      st(768, tanh_fast(ev.x - tx),   tanh_fast(ev.y - ty));
    }
  }
}

extern "C" void kernel_launch(void* const* d_in, const int* in_sizes, int n_in,
                              void* d_out, int out_size, void* d_ws, size_t ws_size,
                              hipStream_t stream) {
  const float* video = (const float*)d_in[0];  // 16x512x1024
  const float* text  = (const float*)d_in[1];  // 16x40x300
  const float* w1    = (const float*)d_in[2];  // 1024x256
  const float* w2    = (const float*)d_in[3];  // 300x256
  const float* w3    = (const float*)d_in[4];  // 256
  const float* bias  = (const float*)d_in[5];  // 256
  const float* w4    = (const float*)d_in[6];  // 1024x500
  const float* b4    = (const float*)d_in[7];  // 500
  float* out = (float*)d_out;                  // 16x512x500
  char* ws = (char*)d_ws;

  // workspace layout (bytes)
  short* video_hi = (short*)(ws);              // 8192x1024 bf16 = 16,777,216
  short* video_lo = (short*)(ws + 16777216);   // 8192x1024 bf16 = 16,777,216 (aliased w/ contbuf)
  short* contbuf  = (short*)(ws + 16777216);   // dead until after e-GEMM consumes video_lo
  short* w1T_hi   = (short*)(ws + 33554432);   // 256x1024 bf16 = 524,288
  short* w1T_lo   = (short*)(ws + 34078720);   // 256x1024 bf16 = 524,288
  short* w4T      = (short*)(ws + 34603008);   // 512x1024 bf16 = 1,048,576 (rows 500..511 zero)
  float* fbuf     = (float*)(ws + 35651584);   // 16x40x256 f32 = 655,360 (f + bias)
  float* ebuf     = (float*)(ws + 36306944);   // 8192x256 f32  = 8,388,608

  k_convert_split<<<2048, 256, 0, stream>>>(video, video_hi, video_lo, 8388608 / 4);
  k_transpose_split<<<dim3(32, 8), 256, 0, stream>>>(w1, w1T_hi, w1T_lo, 1024, 256);
  k_transpose_cvt<<<dim3(32, 16), 256, 0, stream>>>(w4, w4T, 1024, 500);
  k_fb<<<dim3(16, 5), 256, 0, stream>>>(text, w2, bias, fbuf);
  k_gemm_split<<<dim3(128, 4), 256, 0, stream>>>(video_hi, video_lo, w1T_hi, w1T_lo,
                                                 ebuf, 1024, 256);
  k_middle<<<1024, 320, 0, stream>>>(ebuf, fbuf, w3, bias, contbuf);
  k_gemm<<<dim3(128, 8), 256, 0, stream>>>(contbuf, w4T, b4, out, 1024, 500, 500);
}

// Round 3
// 214.487 us; speedup vs baseline: 1.1381x; 1.1381x over previous
//
#include <hip/hip_runtime.h>
#include <hip/hip_bf16.h>
#include <cstdint>

typedef __attribute__((ext_vector_type(8))) short bf16x8;
typedef __attribute__((ext_vector_type(4))) short bf16x4;
typedef __attribute__((ext_vector_type(4))) float f32x4;

__device__ __forceinline__ short cvt_bf16(float f) {
  union { float f; uint32_t u; } x; x.f = f;
  uint32_t r = x.u + 0x7FFFu + ((x.u >> 16) & 1u);  // RNE
  return (short)(r >> 16);
}
__device__ __forceinline__ float bf16_to_f(short s) {
  union { uint32_t u; float f; } x; x.u = ((uint32_t)(uint16_t)s) << 16;
  return x.f;
}

// tanh(x) = 1 - 2/(e^{2x}+1); exp2 form never overflows the denominator.
__device__ __forceinline__ float tanh_fast(float x) {
  float e = __builtin_amdgcn_exp2f(x * 2.8853900817779268f);  // 2*log2(e)
  return 1.0f - 2.0f * __builtin_amdgcn_rcpf(e + 1.0f);
}

// ---------- f32 -> (hi,lo) bf16 split convert ----------
__global__ __launch_bounds__(256) void k_convert_split(const float* __restrict__ in,
                                                       short* __restrict__ hi,
                                                       short* __restrict__ lo, int n4) {
  int i = blockIdx.x * 256 + threadIdx.x;
  int stride = gridDim.x * 256;
  for (; i < n4; i += stride) {
    float4 v = ((const float4*)in)[i];
    bf16x4 h, l;
    h.x = cvt_bf16(v.x); h.y = cvt_bf16(v.y); h.z = cvt_bf16(v.z); h.w = cvt_bf16(v.w);
    l.x = cvt_bf16(v.x - bf16_to_f(h.x));
    l.y = cvt_bf16(v.y - bf16_to_f(h.y));
    l.z = cvt_bf16(v.z - bf16_to_f(h.z));
    l.w = cvt_bf16(v.w - bf16_to_f(h.w));
    ((bf16x4*)hi)[i] = h;
    ((bf16x4*)lo)[i] = l;
  }
}

// ---------- LDS-tiled transpose + f32->bf16 split: out[c*R+r] = in[r*C+c] ----------
__global__ __launch_bounds__(256) void k_transpose_split(const float* __restrict__ in,
                                                         short* __restrict__ hi,
                                                         short* __restrict__ lo,
                                                         int R, int C) {
  __shared__ float tile[32][33];
  int r0 = blockIdx.x * 32, c0 = blockIdx.y * 32;
  int j = threadIdx.x & 31, i0 = threadIdx.x >> 5;
  #pragma unroll
  for (int i = i0; i < 32; i += 8) {
    int c = c0 + j;
    tile[i][j] = (c < C) ? in[(size_t)(r0 + i) * C + c] : 0.f;
  }
  __syncthreads();
  #pragma unroll
  for (int i = i0; i < 32; i += 8) {
    float v = tile[j][i];
    short h = cvt_bf16(v);
    hi[(size_t)(c0 + i) * R + r0 + j] = h;
    lo[(size_t)(c0 + i) * R + r0 + j] = cvt_bf16(v - bf16_to_f(h));
  }
}

// ---------- plain transpose + cvt (for w4, zero-pad cols >= C) ----------
__global__ __launch_bounds__(256) void k_transpose_cvt(const float* __restrict__ in,
                                                       short* __restrict__ out,
                                                       int R, int C) {
  __shared__ float tile[32][33];
  int r0 = blockIdx.x * 32, c0 = blockIdx.y * 32;
  int j = threadIdx.x & 31, i0 = threadIdx.x >> 5;
  #pragma unroll
  for (int i = i0; i < 32; i += 8) {
    int c = c0 + j;
    tile[i][j] = (c < C) ? in[(size_t)(r0 + i) * C + c] : 0.f;
  }
  __syncthreads();
  #pragma unroll
  for (int i = i0; i < 32; i += 8)
    out[(size_t)(c0 + i) * R + r0 + j] = cvt_bf16(tile[j][i]);
}

// ---------- fb[b][t][a] = text[b,t,:] . w2[:,a] + bias[a]  (K=300, exact f32) ----------
__global__ __launch_bounds__(256) void k_fb(const float* __restrict__ text,
                                            const float* __restrict__ w2,
                                            const float* __restrict__ bias,
                                            float* __restrict__ fb) {
  int b = blockIdx.x, t0 = blockIdx.y * 8, a = threadIdx.x;
  float acc[8] = {0.f,0.f,0.f,0.f,0.f,0.f,0.f,0.f};
  const float* tp = text + ((size_t)b * 40 + t0) * 300;
  for (int k = 0; k < 300; k++) {
    float wv = w2[k * 256 + a];
    #pragma unroll
    for (int j = 0; j < 8; j++) acc[j] += tp[j * 300 + k] * wv;
  }
  float bv = bias[a];
  #pragma unroll
  for (int j = 0; j < 8; j++)
    fb[((size_t)b * 40 + t0 + j) * 256 + a] = acc[j] + bv;
}

// ---------- bf16 MFMA GEMM: C[MxN(ldc)] = A[MxK] * BT[NxK]^T (+bias) ----------
__global__ __launch_bounds__(256) void k_gemm(const short* __restrict__ A,
                                              const short* __restrict__ BT,
                                              const float* __restrict__ bias,
                                              float* __restrict__ C,
                                              int K, int ldc, int nstore) {
  __shared__ __align__(16) short As[64][72];
  __shared__ __align__(16) short Bs[64][72];
  int m0 = blockIdx.x * 64, n0 = blockIdx.y * 64;
  int tid = threadIdx.x, lane = tid & 63, wave = tid >> 6;
  int wm = (wave & 1) * 32, wn = (wave >> 1) * 32;
  int srow = tid >> 3, sseg = (tid & 7) * 8;
  f32x4 acc[2][2];
  #pragma unroll
  for (int i = 0; i < 2; i++)
    #pragma unroll
    for (int j = 0; j < 2; j++) acc[i][j] = (f32x4){0.f, 0.f, 0.f, 0.f};
  int mrow = lane & 15, quad = lane >> 4;

  for (int k0 = 0; k0 < K; k0 += 64) {
    bf16x8 a0 = *(const bf16x8*)(A + (size_t)(m0 + srow) * K + k0 + sseg);
    bf16x8 a1 = *(const bf16x8*)(A + (size_t)(m0 + srow + 32) * K + k0 + sseg);
    bf16x8 b0 = *(const bf16x8*)(BT + (size_t)(n0 + srow) * K + k0 + sseg);
    bf16x8 b1 = *(const bf16x8*)(BT + (size_t)(n0 + srow + 32) * K + k0 + sseg);
    __syncthreads();
    *(bf16x8*)&As[srow][sseg] = a0;
    *(bf16x8*)&As[srow + 32][sseg] = a1;
    *(bf16x8*)&Bs[srow][sseg] = b0;
    *(bf16x8*)&Bs[srow + 32][sseg] = b1;
    __syncthreads();
    #pragma unroll
    for (int ks = 0; ks < 2; ks++) {
      int kk = ks * 32 + quad * 8;
      bf16x8 af0 = *(const bf16x8*)&As[wm + mrow][kk];
      bf16x8 af1 = *(const bf16x8*)&As[wm + 16 + mrow][kk];
      bf16x8 bf0 = *(const bf16x8*)&Bs[wn + mrow][kk];
      bf16x8 bf1 = *(const bf16x8*)&Bs[wn + 16 + mrow][kk];
      acc[0][0] = __builtin_amdgcn_mfma_f32_16x16x32_bf16(af0, bf0, acc[0][0], 0, 0, 0);
      acc[0][1] = __builtin_amdgcn_mfma_f32_16x16x32_bf16(af0, bf1, acc[0][1], 0, 0, 0);
      acc[1][0] = __builtin_amdgcn_mfma_f32_16x16x32_bf16(af1, bf0, acc[1][0], 0, 0, 0);
      acc[1][1] = __builtin_amdgcn_mfma_f32_16x16x32_bf16(af1, bf1, acc[1][1], 0, 0, 0);
    }
  }
  int rbase = quad * 4;
  #pragma unroll
  for (int i = 0; i < 2; i++)
    #pragma unroll
    for (int j = 0; j < 2; j++) {
      int col = n0 + wn + j * 16 + mrow;
      if (col < nstore) {
        float bv = bias ? bias[col] : 0.f;
        #pragma unroll
        for (int r = 0; r < 4; r++) {
          int row = m0 + wm + i * 16 + rbase + r;
          C[(size_t)row * ldc + col] = acc[i][j][r] + bv;
        }
      }
    }
}

// ---------- split-bf16 MFMA GEMM (~f32 precision): C = (Ah+Al) * (Bh+Bl)^T ----------
__global__ __launch_bounds__(256) void k_gemm_split(const short* __restrict__ Ah,
                                                    const short* __restrict__ Al,
                                                    const short* __restrict__ BTh,
                                                    const short* __restrict__ BTl,
                                                    float* __restrict__ C,
                                                    int K, int ldc) {
  __shared__ __align__(16) short Ash[64][72];
  __shared__ __align__(16) short Asl[64][72];
  __shared__ __align__(16) short Bsh[64][72];
  __shared__ __align__(16) short Bsl[64][72];
  int m0 = blockIdx.x * 64, n0 = blockIdx.y * 64;
  int tid = threadIdx.x, lane = tid & 63, wave = tid >> 6;
  int wm = (wave & 1) * 32, wn = (wave >> 1) * 32;
  int srow = tid >> 3, sseg = (tid & 7) * 8;
  f32x4 acc[2][2];
  #pragma unroll
  for (int i = 0; i < 2; i++)
    #pragma unroll
    for (int j = 0; j < 2; j++) acc[i][j] = (f32x4){0.f, 0.f, 0.f, 0.f};
  int mrow = lane & 15, quad = lane >> 4;

  for (int k0 = 0; k0 < K; k0 += 64) {
    size_t aoff0 = (size_t)(m0 + srow) * K + k0 + sseg;
    size_t aoff1 = aoff0 + (size_t)32 * K;
    size_t boff0 = (size_t)(n0 + srow) * K + k0 + sseg;
    size_t boff1 = boff0 + (size_t)32 * K;
    bf16x8 a0h = *(const bf16x8*)(Ah + aoff0);
    bf16x8 a1h = *(const bf16x8*)(Ah + aoff1);
    bf16x8 a0l = *(const bf16x8*)(Al + aoff0);
    bf16x8 a1l = *(const bf16x8*)(Al + aoff1);
    bf16x8 b0h = *(const bf16x8*)(BTh + boff0);
    bf16x8 b1h = *(const bf16x8*)(BTh + boff1);
    bf16x8 b0l = *(const bf16x8*)(BTl + boff0);
    bf16x8 b1l = *(const bf16x8*)(BTl + boff1);
    __syncthreads();
    *(bf16x8*)&Ash[srow][sseg] = a0h;  *(bf16x8*)&Ash[srow + 32][sseg] = a1h;
    *(bf16x8*)&Asl[srow][sseg] = a0l;  *(bf16x8*)&Asl[srow + 32][sseg] = a1l;
    *(bf16x8*)&Bsh[srow][sseg] = b0h;  *(bf16x8*)&Bsh[srow + 32][sseg] = b1h;
    *(bf16x8*)&Bsl[srow][sseg] = b0l;  *(bf16x8*)&Bsl[srow + 32][sseg] = b1l;
    __syncthreads();
    #pragma unroll
    for (int ks = 0; ks < 2; ks++) {
      int kk = ks * 32 + quad * 8;
      bf16x8 ah[2], al[2], bh[2], bl[2];
      ah[0] = *(const bf16x8*)&Ash[wm + mrow][kk];
      ah[1] = *(const bf16x8*)&Ash[wm + 16 + mrow][kk];
      al[0] = *(const bf16x8*)&Asl[wm + mrow][kk];
      al[1] = *(const bf16x8*)&Asl[wm + 16 + mrow][kk];
      bh[0] = *(const bf16x8*)&Bsh[wn + mrow][kk];
      bh[1] = *(const bf16x8*)&Bsh[wn + 16 + mrow][kk];
      bl[0] = *(const bf16x8*)&Bsl[wn + mrow][kk];
      bl[1] = *(const bf16x8*)&Bsl[wn + 16 + mrow][kk];
      #pragma unroll
      for (int i = 0; i < 2; i++)
        #pragma unroll
        for (int j = 0; j < 2; j++) {
          acc[i][j] = __builtin_amdgcn_mfma_f32_16x16x32_bf16(ah[i], bh[j], acc[i][j], 0, 0, 0);
          acc[i][j] = __builtin_amdgcn_mfma_f32_16x16x32_bf16(ah[i], bl[j], acc[i][j], 0, 0, 0);
          acc[i][j] = __builtin_amdgcn_mfma_f32_16x16x32_bf16(al[i], bh[j], acc[i][j], 0, 0, 0);
        }
    }
  }
  int rbase = quad * 4;
  #pragma unroll
  for (int i = 0; i < 2; i++)
    #pragma unroll
    for (int j = 0; j < 2; j++) {
      int col = n0 + wn + j * 16 + mrow;
      #pragma unroll
      for (int r = 0; r < 4; r++) {
        int row = m0 + wm + i * 16 + rbase + r;
        C[(size_t)row * ldc + col] = acc[i][j][r];
      }
    }
}

// ---------- fused middle, wave-per-row: logits -> softmax -> text_attn -> tanh(cont) ----------
// block = 512 threads = 8 waves = 8 s1-rows. Lane owns a-quad (a = 4*lane); e/w3/bias in regs.
// LDS: fb slab (40 KB) + lg/attn rows => ~43.5 KB => 3 blocks/CU (24 waves, 75% occupancy).
// All post-staging phases are wave-local: no __syncthreads in the hot path.
__global__ __launch_bounds__(512) void k_middle(const float* __restrict__ e,
                                                const float* __restrict__ fb,
                                                const float* __restrict__ w3,
                                                const float* __restrict__ bias,
                                                short* __restrict__ cont) {
  __shared__ __align__(16) float fbs[40 * 256];
  __shared__ float lg[8][40];
  __shared__ float attn[8][40];
  int tid = threadIdx.x, wave = tid >> 6, lane = tid & 63;
  int row0 = blockIdx.x * 8;
  int b = row0 >> 9;          // 512 rows per batch
  int row = row0 + wave;

  // stage fb (= f + bias) slab for this batch: 2560 float4 loads over 512 threads
  const float4* fsrc = (const float4*)(fb + (size_t)b * 40 * 256);
  #pragma unroll
  for (int i = tid; i < 40 * 64; i += 512) ((float4*)fbs)[i] = fsrc[i];
  __syncthreads();

  int a0 = lane * 4;
  float4 e4  = *(const float4*)(e + (size_t)row * 256 + a0);
  float4 w34 = *(const float4*)(w3 + a0);
  float4 bv4 = *(const float4*)(bias + a0);

  // phase 1: logits. Each lane: 4-elem tanh-dot, then 6-step butterfly reduce.
  for (int t = 0; t < 40; t++) {
    float4 f4 = *(const float4*)&fbs[t * 256 + a0];
    float p = tanh_fast(e4.x + f4.x) * w34.x
            + tanh_fast(e4.y + f4.y) * w34.y
            + tanh_fast(e4.z + f4.z) * w34.z
            + tanh_fast(e4.w + f4.w) * w34.w;
    #pragma unroll
    for (int s = 32; s >= 1; s >>= 1) p += __shfl_xor(p, s, 64);
    if (lane == 0) lg[wave][t] = p;
  }

  // phase 2: softmax over t (wave-local; lanes >= 40 idle via -inf/0)
  {
    float x = (lane < 40) ? lg[wave][lane] : -3.0e38f;
    float m = x;
    #pragma unroll
    for (int s = 32; s >= 1; s >>= 1) m = fmaxf(m, __shfl_xor(m, s, 64));
    float ex = (lane < 40) ? __builtin_amdgcn_exp2f((x - m) * 1.4426950408889634f) : 0.f;
    float ssum = ex;
    #pragma unroll
    for (int s = 32; s >= 1; s >>= 1) ssum += __shfl_xor(ssum, s, 64);
    if (lane < 40) attn[wave][lane] = ex * __builtin_amdgcn_rcpf(ssum);
  }

  // phase 3: text_attn chunk = sum_t attn[t] * fbs[t][chunk]  (then - bias; sum attn = 1)
  float tax = 0.f, tay = 0.f, taz = 0.f, taw = 0.f;
  for (int t = 0; t < 40; t++) {
    float w = attn[wave][t];  // wave-uniform broadcast read
    float4 f4 = *(const float4*)&fbs[t * 256 + a0];
    tax += w * f4.x; tay += w * f4.y; taz += w * f4.z; taw += w * f4.w;
  }
  tax -= bv4.x; tay -= bv4.y; taz -= bv4.z; taw -= bv4.w;

  // cont segments -> tanh -> bf16, 8B stores (4 shorts), coalesced across lanes
  short* crow = cont + (size_t)row * 1024 + a0;
  auto st4 = [&](int off, float x, float y, float z, float w) {
    uint32_t lo = (uint32_t)(uint16_t)cvt_bf16(x) | ((uint32_t)(uint16_t)cvt_bf16(y) << 16);
    uint32_t hi = (uint32_t)(uint16_t)cvt_bf16(z) | ((uint32_t)(uint16_t)cvt_bf16(w) << 16);
    uint2 p; p.x = lo; p.y = hi;
    *(uint2*)(crow + off) = p;
  };
  st4(0,   tanh_fast(e4.x), tanh_fast(e4.y), tanh_fast(e4.z), tanh_fast(e4.w));
  st4(256, tanh_fast(tax),  tanh_fast(tay),  tanh_fast(taz),  tanh_fast(taw));
  st4(512, tanh_fast(e4.x * tax), tanh_fast(e4.y * tay),
           tanh_fast(e4.z * taz), tanh_fast(e4.w * taw));
  st4(768, tanh_fast(e4.x - tax), tanh_fast(e4.y - tay),
           tanh_fast(e4.z - taz), tanh_fast(e4.w - taw));
}

extern "C" void kernel_launch(void* const* d_in, const int* in_sizes, int n_in,
                              void* d_out, int out_size, void* d_ws, size_t ws_size,
                              hipStream_t stream) {
  const float* video = (const float*)d_in[0];  // 16x512x1024
  const float* text  = (const float*)d_in[1];  // 16x40x300
  const float* w1    = (const float*)d_in[2];  // 1024x256
  const float* w2    = (const float*)d_in[3];  // 300x256
  const float* w3    = (const float*)d_in[4];  // 256
  const float* bias  = (const float*)d_in[5];  // 256
  const float* w4    = (const float*)d_in[6];  // 1024x500
  const float* b4    = (const float*)d_in[7];  // 500
  float* out = (float*)d_out;                  // 16x512x500
  char* ws = (char*)d_ws;

  // workspace layout (bytes)
  short* video_hi = (short*)(ws);              // 8192x1024 bf16 = 16,777,216
  short* video_lo = (short*)(ws + 16777216);   // 8192x1024 bf16 = 16,777,216 (aliased w/ contbuf)
  short* contbuf  = (short*)(ws + 16777216);   // dead until after e-GEMM consumes video_lo
  short* w1T_hi   = (short*)(ws + 33554432);   // 256x1024 bf16 = 524,288
  short* w1T_lo   = (short*)(ws + 34078720);   // 256x1024 bf16 = 524,288
  short* w4T      = (short*)(ws + 34603008);   // 512x1024 bf16 = 1,048,576 (rows 500..511 zero)
  float* fbuf     = (float*)(ws + 35651584);   // 16x40x256 f32 = 655,360 (f + bias)
  float* ebuf     = (float*)(ws + 36306944);   // 8192x256 f32  = 8,388,608

  k_convert_split<<<2048, 256, 0, stream>>>(video, video_hi, video_lo, 8388608 / 4);
  k_transpose_split<<<dim3(32, 8), 256, 0, stream>>>(w1, w1T_hi, w1T_lo, 1024, 256);
  k_transpose_cvt<<<dim3(32, 16), 256, 0, stream>>>(w4, w4T, 1024, 500);
  k_fb<<<dim3(16, 5), 256, 0, stream>>>(text, w2, bias, fbuf);
  k_gemm_split<<<dim3(128, 4), 256, 0, stream>>>(video_hi, video_lo, w1T_hi, w1T_lo,
                                                 ebuf, 1024, 256);
  k_middle<<<1024, 512, 0, stream>>>(ebuf, fbuf, w3, bias, contbuf);
  k_gemm<<<dim3(128, 8), 256, 0, stream>>>(contbuf, w4T, b4, out, 1024, 500, 500);
}